// Round 2
// baseline (35260.019 us; speedup 1.0000x reference)
//
#include <hip/hip_runtime.h>

#define Bb 8
#define Ss 4096
#define Dd 512
#define Hh 1024
#define CSc 64
#define NCn 64
#define MROW 512  // Bb*CSc

enum { PH_PROJ=0, PH_H1, PH_PRED, PH_D1, PH_UPD1, PH_UPD2, PH_H1Q, PH_R, PH_OUTC };

struct Ptrs {
  const float *x, *Wk, *Wv, *Wq, *Wout, *W1, *W2;
  float *kbuf, *vbuf, *qbuf, *rbuf;
  float *h1, *a1, *d1b, *d2b;
  float *Wd1, *M1, *Wd2, *M2;
  float *gates;
  float *out;
  int nc;
};

__device__ __forceinline__ float sig_(float v){ return 1.0f/(1.0f+__expf(-v)); }
__device__ __forceinline__ float silu_(float v){ return v*sig_(v); }
__device__ __forceinline__ float dsilu_(float v){ float s=sig_(v); return s*(1.0f + v*(1.0f-s)); }
__device__ __forceinline__ float clip1_(float v){ return fminf(fmaxf(v,-1.0f),1.0f); }
// row index m=(b,c) -> flat [b*S + nc*64 + c]*D + d
__device__ __forceinline__ size_t cidx(int m, int d, int nc){
  return ((size_t)((m>>6)*Ss) + nc*CSc + (m&63))*Dd + d;
}

// ---------------- generic tiled fp32 GEMM with phase-fused epilogues -------------
template<int PHASE, int BM, int BN, int BK, int KD>
__global__ __launch_bounds__(256)
void gk(Ptrs p) {
  constexpr int TM = BM/16, TN = BN/16;
  constexpr int SA = BM+4, SB = BN+4;
  __shared__ float As[BK][SA];
  __shared__ float Bs[BK][SB];
  const int tid = threadIdx.x;
  const int tx = tid & 15, ty = tid >> 4;
  const int m0 = blockIdx.x * BM;
  const int n0 = blockIdx.y * BN;
  const int nc = p.nc;

  const float* Wp = nullptr; float* Cp = nullptr;
  if constexpr (PHASE==PH_PROJ) {
    int z = blockIdx.z;
    Wp = (z==0) ? p.Wk : (z==1 ? p.Wv : p.Wq);
    Cp = (z==0) ? p.kbuf : (z==1 ? p.vbuf : p.qbuf);
  }

  float acc[TM][TN];
  #pragma unroll
  for (int i=0;i<TM;i++)
    #pragma unroll
    for (int j=0;j<TN;j++) acc[i][j]=0.0f;

  for (int k0 = 0; k0 < KD; k0 += BK) {
    // ---- stage A ----
    if constexpr (PHASE==PH_UPD1 || PHASE==PH_UPD2) {
      // transposed mode: A[k][m], k = token index
      for (int e = tid; e < BK*BM; e += 256) {
        int kk = e / BM, mm = e % BM;
        float v;
        if constexpr (PHASE==PH_UPD1) v = p.d1b[(size_t)(k0+kk)*Hh + (m0+mm)];
        else                          v = p.d2b[(size_t)(k0+kk)*Dd + (m0+mm)];
        As[kk][mm] = v;
      }
    } else {
      for (int e = tid; e < BM*BK; e += 256) {
        int mm = e / BK, kk = e % BK;
        int m = m0+mm, k = k0+kk;
        float v;
        if constexpr (PHASE==PH_PROJ)      v = p.x[(size_t)m*Dd + k];
        else if constexpr (PHASE==PH_OUTC) v = p.rbuf[(size_t)m*Dd + k];
        else if constexpr (PHASE==PH_H1)   v = p.kbuf[cidx(m,k,nc)];
        else if constexpr (PHASE==PH_H1Q)  v = p.qbuf[cidx(m,k,nc)];
        else if constexpr (PHASE==PH_PRED) v = p.a1[(size_t)m*Hh + k];
        else if constexpr (PHASE==PH_R)    v = p.d1b[(size_t)m*Hh + k];
        else /*PH_D1*/                     v = p.d2b[(size_t)m*Dd + k];
        As[kk][mm] = v;
      }
    }
    // ---- stage B ----
    if constexpr (PHASE==PH_D1) {
      for (int e = tid; e < BK*BN; e += 256) {
        int kk = e / BN, nn = e % BN;
        int k = k0+kk, n = n0+nn;
        Bs[kk][nn] = p.W2[(size_t)k*Hh+n] + p.Wd2[(size_t)k*Hh+n];
      }
    } else if constexpr (PHASE==PH_UPD1) {
      for (int e = tid; e < BK*BN; e += 256) {
        int kk = e / BN, nn = e % BN;
        Bs[kk][nn] = p.kbuf[cidx(k0+kk, n0+nn, nc)];
      }
    } else if constexpr (PHASE==PH_UPD2) {
      for (int e = tid; e < BK*BN; e += 256) {
        int kk = e / BN, nn = e % BN;
        Bs[kk][nn] = p.a1[(size_t)(k0+kk)*Hh + (n0+nn)];
      }
    } else {
      for (int e = tid; e < BN*BK; e += 256) {
        int nn = e / BK, kk = e % BK;
        int n = n0+nn, k = k0+kk;
        float v;
        if constexpr (PHASE==PH_PROJ)      v = Wp[(size_t)n*Dd+k];
        else if constexpr (PHASE==PH_OUTC) v = p.Wout[(size_t)n*Dd+k];
        else if constexpr (PHASE==PH_H1 || PHASE==PH_H1Q)
                                           v = p.W1[(size_t)n*Dd+k] + p.Wd1[(size_t)n*Dd+k];
        else /*PRED,R*/                    v = p.W2[(size_t)n*Hh+k] + p.Wd2[(size_t)n*Hh+k];
        Bs[kk][nn] = v;
      }
    }
    __syncthreads();
    // ---- compute ----
    #pragma unroll
    for (int kk=0; kk<BK; ++kk) {
      float a[TM], b[TN];
      if constexpr (TM==4) { float4 t = *(const float4*)&As[kk][ty*4]; a[0]=t.x;a[1]=t.y;a[2]=t.z;a[3]=t.w; }
      else                 { float2 t = *(const float2*)&As[kk][ty*2]; a[0]=t.x;a[1]=t.y; }
      if constexpr (TN==4) { float4 t = *(const float4*)&Bs[kk][tx*4]; b[0]=t.x;b[1]=t.y;b[2]=t.z;b[3]=t.w; }
      else                 { float2 t = *(const float2*)&Bs[kk][tx*2]; b[0]=t.x;b[1]=t.y; }
      #pragma unroll
      for (int i=0;i<TM;i++)
        #pragma unroll
        for (int j=0;j<TN;j++) acc[i][j] += a[i]*b[j];
    }
    __syncthreads();
  }

  // ---- epilogue ----
  #pragma unroll
  for (int i=0;i<TM;i++){
    int m = m0 + ty*TM + i;
    #pragma unroll
    for (int j=0;j<TN;j++){
      int n = n0 + tx*TN + j;
      float v = acc[i][j];
      if constexpr (PHASE==PH_PROJ)      Cp[(size_t)m*Dd+n] = v;
      else if constexpr (PHASE==PH_OUTC) p.out[cidx(m,n,nc)] = v;
      else if constexpr (PHASE==PH_H1) { p.h1[(size_t)m*Hh+n]=v; p.a1[(size_t)m*Hh+n]=silu_(v); }
      else if constexpr (PHASE==PH_H1Q){ p.d1b[(size_t)m*Hh+n] = silu_(v); }
      else if constexpr (PHASE==PH_PRED){
        float e = clip1_(v - p.vbuf[cidx(m,n,nc)]);
        p.d2b[(size_t)m*Dd+n] = 0.03125f*e;        // scale = 2/CS
      }
      else if constexpr (PHASE==PH_R)  { p.rbuf[(size_t)m*Dd+n] = v; }   // compact [512,512]
      else if constexpr (PHASE==PH_D1) { p.d1b[(size_t)m*Hh+n] = v * dsilu_(p.h1[(size_t)m*Hh+n]); }
      else if constexpr (PHASE==PH_UPD1){
        float g = clip1_(v);
        float al = p.gates[nc], lr = p.gates[NCn+nc], et = p.gates[2*NCn+nc];
        size_t idx = (size_t)m*Dd+n;
        float m1 = et*p.M1[idx] - lr*g;
        p.M1[idx] = m1;
        p.Wd1[idx] = (1.0f-al)*p.Wd1[idx] + m1;
      }
      else if constexpr (PHASE==PH_UPD2){
        float g = clip1_(v);
        float al = p.gates[nc], lr = p.gates[NCn+nc], et = p.gates[2*NCn+nc];
        size_t idx = (size_t)m*Hh+n;
        float m2 = et*p.M2[idx] - lr*g;
        p.M2[idx] = m2;
        p.Wd2[idx] = (1.0f-al)*p.Wd2[idx] + m2;
      }
    }
  }
}

// ---------------- zero the scan state (replaces hipMemsetAsync) ------------------
__global__ __launch_bounds__(256)
void zero_k(float* __restrict__ ptr, int n){
  int i = blockIdx.x*256 + threadIdx.x;
  int stride = gridDim.x*256;
  for (; i < n; i += stride) ptr[i] = 0.0f;
}

// ---------------- halo save (last 3 rows of each chunk, pre-conv values) ---------
__global__ void halo_k(const float* __restrict__ kbuf, const float* __restrict__ vbuf,
                       const float* __restrict__ qbuf, float* __restrict__ halo){
  int bid = blockIdx.x;
  int t = bid / (NCn*Bb);
  int rem = bid % (NCn*Bb);
  int nc = rem / Bb, b = rem % Bb;
  const float* src = (t==0)?kbuf:((t==1)?vbuf:qbuf);
  float* dst = halo + (((size_t)t*NCn + nc)*Bb + b)*3*Dd;
  for (int e = threadIdx.x; e < 3*Dd; e += 256){
    int j = e / Dd, d = e % Dd;
    int s = nc*CSc + 61 + j;
    dst[e] = src[((size_t)b*Ss + s)*Dd + d];
  }
}

// ---------------- in-place causal depthwise conv (K=4) --------------------------
__global__ void conv_k(float* __restrict__ kbuf, float* __restrict__ vbuf, float* __restrict__ qbuf,
                       const float* __restrict__ ckw, const float* __restrict__ ckb,
                       const float* __restrict__ cvw, const float* __restrict__ cvb,
                       const float* __restrict__ cqw, const float* __restrict__ cqb,
                       const float* __restrict__ halo){
  int bid = blockIdx.x;
  int t = bid / (NCn*Bb);
  int rem = bid % (NCn*Bb);
  int nc = rem / Bb, b = rem % Bb;
  float* buf = (t==0)?kbuf:((t==1)?vbuf:qbuf);
  const float* cw = (t==0)?ckw:((t==1)?cvw:cqw);
  const float* cb = (t==0)?ckb:((t==1)?cvb:cqb);
  const float* hl = halo + (((size_t)t*NCn + (nc>0?nc-1:0))*Bb + b)*3*Dd;
  for (int rep=0; rep<2; ++rep){
    int d = threadIdx.x + rep*256;
    float w0 = cw[d*4+0], w1 = cw[d*4+1], w2 = cw[d*4+2], w3 = cw[d*4+3];
    float bias = cb[d];
    float p1, p2, p3;   // in[s-1], in[s-2], in[s-3]
    if (nc == 0) { p1=p2=p3=0.0f; }
    else { p1 = hl[2*Dd+d]; p2 = hl[1*Dd+d]; p3 = hl[0*Dd+d]; }
    float* row = buf + ((size_t)b*Ss + nc*CSc)*Dd + d;
    for (int c=0;c<CSc;++c){
      float cur = row[(size_t)c*Dd];
      float o = w3*cur + w2*p1 + w1*p2 + w0*p3 + bias;
      p3 = p2; p2 = p1; p1 = cur;
      row[(size_t)c*Dd] = o;
    }
  }
}

// ---------------- per-chunk scalar gates ----------------------------------------
__global__ __launch_bounds__(256)
void gates_k(const float* __restrict__ x,
             const float* __restrict__ wd, const float* __restrict__ bd,
             const float* __restrict__ wl, const float* __restrict__ bl,
             const float* __restrict__ we, const float* __restrict__ be,
             float* __restrict__ gates){
  int nc = blockIdx.x;
  int wave = threadIdx.x >> 6, lane = threadIdx.x & 63;
  __shared__ float red[4][3];
  float accA=0.f, accL=0.f, accE=0.f;
  float bdv = bd[0], blv = bl[0], bev = be[0];
  for (int pi = wave; pi < Bb*CSc; pi += 4) {
    int b = pi / CSc, c = pi % CSc;
    const float* xr = x + ((size_t)b*Ss + nc*CSc + c)*Dd + lane*8;
    float da=0.f, dl=0.f, de=0.f;
    #pragma unroll
    for (int u=0;u<8;++u){
      float xv = xr[u];
      int d = lane*8+u;
      da += xv*wd[d]; dl += xv*wl[d]; de += xv*we[d];
    }
    #pragma unroll
    for (int off=32; off; off>>=1){
      da += __shfl_down(da, off);
      dl += __shfl_down(dl, off);
      de += __shfl_down(de, off);
    }
    if (lane==0){
      accA += sig_(da + bdv);
      accL += sig_(dl + blv);
      accE += sig_(de + bev);
    }
  }
  if (lane==0){ red[wave][0]=accA; red[wave][1]=accL; red[wave][2]=accE; }
  __syncthreads();
  if (threadIdx.x==0){
    float a=0.f,l=0.f,e=0.f;
    for (int w=0;w<4;w++){ a+=red[w][0]; l+=red[w][1]; e+=red[w][2]; }
    gates[nc]        = a*(1.0f/512.0f);
    gates[NCn+nc]    = l*(1.0f/512.0f);
    gates[2*NCn+nc]  = e*(1.0f/512.0f);
  }
}

extern "C" void kernel_launch(void* const* d_in, const int* in_sizes, int n_in,
                              void* d_out, int out_size, void* d_ws, size_t ws_size,
                              hipStream_t stream) {
  (void)in_sizes; (void)n_in; (void)out_size;
  const float* x       = (const float*)d_in[0];
  const float* Wk      = (const float*)d_in[1];
  const float* Wv      = (const float*)d_in[2];
  const float* Wq      = (const float*)d_in[3];
  const float* Wout    = (const float*)d_in[4];
  const float* ckw     = (const float*)d_in[5];
  const float* ckb     = (const float*)d_in[6];
  const float* cvw     = (const float*)d_in[7];
  const float* cvb     = (const float*)d_in[8];
  const float* cqw     = (const float*)d_in[9];
  const float* cqb     = (const float*)d_in[10];
  const float* w_decay = (const float*)d_in[11];
  const float* b_decay = (const float*)d_in[12];
  const float* w_lr    = (const float*)d_in[13];
  const float* b_lr    = (const float*)d_in[14];
  const float* w_eta   = (const float*)d_in[15];
  const float* b_eta   = (const float*)d_in[16];
  const float* W1      = (const float*)d_in[17];
  const float* W2      = (const float*)d_in[18];

  float* ws = (float*)d_ws;
  size_t o = 0;
  const size_t BSD = (size_t)Bb*Ss*Dd;        // 16,777,216 floats
  float* kbuf = ws + o; o += BSD;
  float* vbuf = ws + o; o += BSD;
  float* halo = ws + o; o += (size_t)3*NCn*Bb*3*Dd;   // 2,359,296
  float* h1   = ws + o; o += (size_t)MROW*Hh;
  float* a1   = ws + o; o += (size_t)MROW*Hh;
  float* d1b  = ws + o; o += (size_t)MROW*Hh;
  float* d2b  = ws + o; o += (size_t)MROW*Dd;
  float* rbuf = ws + o; o += (size_t)MROW*Dd;         // compact per-chunk r
  float* Wd1  = ws + o; o += (size_t)Hh*Dd;
  float* M1   = ws + o; o += (size_t)Hh*Dd;
  float* Wd2  = ws + o; o += (size_t)Dd*Hh;
  float* M2   = ws + o; o += (size_t)Dd*Hh;
  float* gates= ws + o; o += 3*NCn;

  // workspace guard: fail cleanly (no launch) instead of faulting
  if (ws_size < o * sizeof(float)) return;

  // q projection + conv staged in d_out (consumed before output rows written)
  float* qbuf = (float*)d_out;

  // zero the scan state (Wd1,M1,Wd2,M2 contiguous: 4*H*D floats)
  zero_k<<<512, 256, 0, stream>>>(Wd1, 4*Hh*Dd);

  Ptrs p;
  p.x=x; p.Wk=Wk; p.Wv=Wv; p.Wq=Wq; p.Wout=Wout; p.W1=W1; p.W2=W2;
  p.kbuf=kbuf; p.vbuf=vbuf; p.qbuf=qbuf; p.rbuf=rbuf;
  p.h1=h1; p.a1=a1; p.d1b=d1b; p.d2b=d2b;
  p.Wd1=Wd1; p.M1=M1; p.Wd2=Wd2; p.M2=M2;
  p.gates=gates; p.out=(float*)d_out; p.nc=0;

  // projections: k/v/q = x @ W^T   [32768,512]x[512,512]
  gk<PH_PROJ,64,64,16,Dd><<<dim3(Bb*Ss/64, Dd/64, 3), 256, 0, stream>>>(p);
  // halo save + in-place causal conv
  halo_k<<<3*NCn*Bb, 256, 0, stream>>>(kbuf, vbuf, qbuf, halo);
  conv_k<<<3*NCn*Bb, 256, 0, stream>>>(kbuf, vbuf, qbuf, ckw, ckb, cvw, cvb, cqw, cqb, halo);
  // gates
  gates_k<<<NCn, 256, 0, stream>>>(x, w_decay, b_decay, w_lr, b_lr, w_eta, b_eta, gates);

  // sequential chunk scan (8 phases per chunk)
  for (int nc = 0; nc < NCn; ++nc) {
    p.nc = nc;
    gk<PH_H1,  32,64,16,Dd><<<dim3(MROW/32, Hh/64), 256, 0, stream>>>(p);
    gk<PH_PRED,32,32,16,Hh><<<dim3(MROW/32, Dd/32), 256, 0, stream>>>(p);
    gk<PH_D1,  32,64,16,Dd><<<dim3(MROW/32, Hh/64), 256, 0, stream>>>(p);
    gk<PH_UPD1,32,64,16,MROW><<<dim3(Hh/32, Dd/64), 256, 0, stream>>>(p);
    gk<PH_UPD2,32,64,16,MROW><<<dim3(Dd/32, Hh/64), 256, 0, stream>>>(p);
    gk<PH_H1Q, 32,64,16,Dd><<<dim3(MROW/32, Hh/64), 256, 0, stream>>>(p);
    gk<PH_R,   32,32,16,Hh><<<dim3(MROW/32, Dd/32), 256, 0, stream>>>(p);
    gk<PH_OUTC,32,64,16,Dd><<<dim3(MROW/32, Dd/64), 256, 0, stream>>>(p);
  }
}

// Round 3
// 10238.303 us; speedup vs baseline: 3.4439x; 3.4439x over previous
//
#include <hip/hip_runtime.h>

#define Bb 8
#define Ss 4096
#define Dd 512
#define Hh 1024
#define CSc 64
#define NCn 64
#define MROW 512  // Bb*CSc

typedef unsigned short ushort_t;
typedef short s8v __attribute__((ext_vector_type(8)));          // 8 bf16 for MFMA A/B
typedef unsigned short u8v __attribute__((ext_vector_type(8))); // raw 8x bf16 storage
typedef float f4v __attribute__((ext_vector_type(4)));          // MFMA C/D

enum { PH_PROJ=0, PH_H1, PH_PRED, PH_D1, PH_UPD1, PH_UPD2, PH_H1Q, PH_R, PH_OUTC };

struct Ptrs {
  const float *x, *Wk, *Wv, *Wq, *Wout, *W1, *W2;
  ushort_t *kbuf, *vbuf, *qbuf, *rbuf;
  ushort_t *h1, *a1, *d1b, *d2b;
  float *Wd1, *M1, *Wd2, *M2;
  float *gates;
  float *out;
  int nc;
};

__device__ __forceinline__ float b2f(ushort_t u){
  union { unsigned int i; float f; } c; c.i = ((unsigned int)u) << 16; return c.f;
}
__device__ __forceinline__ ushort_t f2b(float f){
  union { float f; unsigned int i; } c; c.f = f;
  unsigned int i = c.i;
  i += 0x7fffu + ((i >> 16) & 1u);   // RTNE
  return (ushort_t)(i >> 16);
}
__device__ __forceinline__ float sig_(float v){ return 1.0f/(1.0f+__expf(-v)); }
__device__ __forceinline__ float silu_(float v){ return v*sig_(v); }
__device__ __forceinline__ float dsilu_(float v){ float s=sig_(v); return s*(1.0f + v*(1.0f-s)); }
__device__ __forceinline__ float clip1_(float v){ return fminf(fmaxf(v,-1.0f),1.0f); }
// row index m=(b,c) -> flat [b*S + nc*64 + c]*D + d
__device__ __forceinline__ size_t cidx(int m, int d, int nc){
  return ((size_t)((m>>6)*Ss) + nc*CSc + (m&63))*Dd + d;
}

// ================= MFMA bf16 GEMM body: 64x64 tile, 4 waves 2x2, BK=32 ==========
template<int PHASE, int KD>
__device__ __forceinline__ void gemm_body(const Ptrs& p, int bx, int by,
                                          const float* Wp, ushort_t* Cp) {
  constexpr int BM=64, BN=64, BK=32, STR=40;   // STR shorts = 80B, 16B-aligned rows
  __shared__ ushort_t As[BM*STR];
  __shared__ ushort_t Bs[BN*STR];
  const int tid = threadIdx.x;
  const int m0 = bx*BM, n0 = by*BN;
  const int nc = p.nc;
  const int wave = tid>>6, lane = tid&63;
  const int wm = wave&1, wn = wave>>1;
  const int quad = lane>>4, l16 = lane&15;

  f4v zz = {0.f,0.f,0.f,0.f};
  f4v acc[2][2];
  acc[0][0]=zz; acc[0][1]=zz; acc[1][0]=zz; acc[1][1]=zz;

  for (int k0=0; k0<KD; k0+=BK) {
    // ---------------- stage A (As[mm][kk], bf16) ----------------
    if constexpr (PHASE==PH_UPD1 || PHASE==PH_UPD2) {
      // A[m][k] = src[k][m] (transposed): read contiguous m, scatter to LDS
      int kk = tid>>3, mm0 = (tid&7)*8;
      const ushort_t* src; int stride;
      if constexpr (PHASE==PH_UPD1){ src = p.d1b; stride = Hh; }
      else                         { src = p.d2b; stride = Dd; }
      u8v v = *(const u8v*)&src[(size_t)(k0+kk)*stride + m0+mm0];
      #pragma unroll
      for (int j=0;j<8;j++) As[(mm0+j)*STR + kk] = v[j];
    } else if constexpr (PHASE==PH_PROJ) {
      int mm = tid>>2, kk0 = (tid&3)*8;
      const float* s = &p.x[(size_t)(m0+mm)*Dd + (k0+kk0)];
      float4 f0 = *(const float4*)s, f1 = *(const float4*)(s+4);
      u8v o; o[0]=f2b(f0.x);o[1]=f2b(f0.y);o[2]=f2b(f0.z);o[3]=f2b(f0.w);
             o[4]=f2b(f1.x);o[5]=f2b(f1.y);o[6]=f2b(f1.z);o[7]=f2b(f1.w);
      *(u8v*)&As[mm*STR + kk0] = o;
    } else {
      int mm = tid>>2, kk0 = (tid&3)*8;
      int m = m0+mm, k = k0+kk0;
      const ushort_t* s;
      if constexpr (PHASE==PH_H1)        s = &p.kbuf[cidx(m,k,nc)];
      else if constexpr (PHASE==PH_H1Q)  s = &p.qbuf[cidx(m,k,nc)];
      else if constexpr (PHASE==PH_PRED) s = &p.a1[(size_t)m*Hh+k];
      else if constexpr (PHASE==PH_R)    s = &p.d1b[(size_t)m*Hh+k];
      else if constexpr (PHASE==PH_D1)   s = &p.d2b[(size_t)m*Dd+k];
      else /*PH_OUTC*/                   s = &p.rbuf[(size_t)m*Dd+k];
      *(u8v*)&As[mm*STR + kk0] = *(const u8v*)s;
    }
    // ---------------- stage B (Bs[nn][kk] = B[k][n] with n-major rows) ----------
    if constexpr (PHASE==PH_D1) {
      // B[n=h][k=d] = E2[d][h]: read 8 consecutive h for fixed d, scatter
      int kk = tid>>3, nn0 = (tid&7)*8;
      size_t off = (size_t)(k0+kk)*Hh + (n0+nn0);
      float4 a0 = *(const float4*)&p.W2[off],  a1_ = *(const float4*)&p.W2[off+4];
      float4 b0 = *(const float4*)&p.Wd2[off], b1_ = *(const float4*)&p.Wd2[off+4];
      Bs[(nn0+0)*STR+kk]=f2b(a0.x+b0.x); Bs[(nn0+1)*STR+kk]=f2b(a0.y+b0.y);
      Bs[(nn0+2)*STR+kk]=f2b(a0.z+b0.z); Bs[(nn0+3)*STR+kk]=f2b(a0.w+b0.w);
      Bs[(nn0+4)*STR+kk]=f2b(a1_.x+b1_.x); Bs[(nn0+5)*STR+kk]=f2b(a1_.y+b1_.y);
      Bs[(nn0+6)*STR+kk]=f2b(a1_.z+b1_.z); Bs[(nn0+7)*STR+kk]=f2b(a1_.w+b1_.w);
    } else if constexpr (PHASE==PH_UPD1) {
      // B[n=d][k=token] = kch[token][d]
      int kk = tid>>3, nn0 = (tid&7)*8;
      u8v v = *(const u8v*)&p.kbuf[cidx(k0+kk, n0+nn0, nc)];
      #pragma unroll
      for (int j=0;j<8;j++) Bs[(nn0+j)*STR + kk] = v[j];
    } else if constexpr (PHASE==PH_UPD2) {
      // B[n=h][k=token] = a1[token][h]
      int kk = tid>>3, nn0 = (tid&7)*8;
      u8v v = *(const u8v*)&p.a1[(size_t)(k0+kk)*Hh + (n0+nn0)];
      #pragma unroll
      for (int j=0;j<8;j++) Bs[(nn0+j)*STR + kk] = v[j];
    } else {
      // row-major fp32 B[n][k] (weights, optionally + Wd)
      int nn = tid>>2, kk0 = (tid&3)*8;
      int n = n0+nn, k = k0+kk0;
      const float *s1, *s2 = nullptr;
      if constexpr (PHASE==PH_PROJ)      { s1 = &Wp[(size_t)n*Dd+k]; }
      else if constexpr (PHASE==PH_OUTC) { s1 = &p.Wout[(size_t)n*Dd+k]; }
      else if constexpr (PHASE==PH_H1 || PHASE==PH_H1Q)
           { s1 = &p.W1[(size_t)n*Dd+k]; s2 = &p.Wd1[(size_t)n*Dd+k]; }
      else /*PRED,R*/
           { s1 = &p.W2[(size_t)n*Hh+k]; s2 = &p.Wd2[(size_t)n*Hh+k]; }
      float4 f0 = *(const float4*)s1, f1 = *(const float4*)(s1+4);
      if (s2) {
        float4 g0 = *(const float4*)s2, g1 = *(const float4*)(s2+4);
        f0.x+=g0.x; f0.y+=g0.y; f0.z+=g0.z; f0.w+=g0.w;
        f1.x+=g1.x; f1.y+=g1.y; f1.z+=g1.z; f1.w+=g1.w;
      }
      u8v o; o[0]=f2b(f0.x);o[1]=f2b(f0.y);o[2]=f2b(f0.z);o[3]=f2b(f0.w);
             o[4]=f2b(f1.x);o[5]=f2b(f1.y);o[6]=f2b(f1.z);o[7]=f2b(f1.w);
      *(u8v*)&Bs[nn*STR + kk0] = o;
    }
    __syncthreads();
    // ---------------- MFMA ----------------
    s8v a0 = *(const s8v*)&As[(wm*32 +  0 + l16)*STR + quad*8];
    s8v a1f= *(const s8v*)&As[(wm*32 + 16 + l16)*STR + quad*8];
    s8v b0 = *(const s8v*)&Bs[(wn*32 +  0 + l16)*STR + quad*8];
    s8v b1f= *(const s8v*)&Bs[(wn*32 + 16 + l16)*STR + quad*8];
    acc[0][0] = __builtin_amdgcn_mfma_f32_16x16x32_bf16(a0,  b0,  acc[0][0], 0,0,0);
    acc[0][1] = __builtin_amdgcn_mfma_f32_16x16x32_bf16(a0,  b1f, acc[0][1], 0,0,0);
    acc[1][0] = __builtin_amdgcn_mfma_f32_16x16x32_bf16(a1f, b0,  acc[1][0], 0,0,0);
    acc[1][1] = __builtin_amdgcn_mfma_f32_16x16x32_bf16(a1f, b1f, acc[1][1], 0,0,0);
    __syncthreads();
  }

  // ---------------- epilogue: D row = quad*4+r, col = l16 ----------------
  float al=0.f, lr=0.f, et=0.f;
  if constexpr (PHASE==PH_UPD1 || PHASE==PH_UPD2) {
    al = p.gates[nc]; lr = p.gates[NCn+nc]; et = p.gates[2*NCn+nc];
  }
  #pragma unroll
  for (int mf=0; mf<2; mf++) {
    #pragma unroll
    for (int nf=0; nf<2; nf++) {
      #pragma unroll
      for (int r=0; r<4; r++) {
        int m = m0 + wm*32 + mf*16 + quad*4 + r;
        int n = n0 + wn*32 + nf*16 + l16;
        float v = acc[mf][nf][r];
        if constexpr (PHASE==PH_PROJ)      Cp[(size_t)m*Dd+n] = f2b(v);
        else if constexpr (PHASE==PH_OUTC) p.out[cidx(m,n,nc)] = v;
        else if constexpr (PHASE==PH_H1) {
          p.h1[(size_t)m*Hh+n] = f2b(v);
          p.a1[(size_t)m*Hh+n] = f2b(silu_(v));
        }
        else if constexpr (PHASE==PH_H1Q)  p.d1b[(size_t)m*Hh+n] = f2b(silu_(v));
        else if constexpr (PHASE==PH_PRED) {
          float e = clip1_(v - b2f(p.vbuf[cidx(m,n,nc)]));
          p.d2b[(size_t)m*Dd+n] = f2b(0.03125f*e);   // scale = 2/CS
        }
        else if constexpr (PHASE==PH_R)    p.rbuf[(size_t)m*Dd+n] = f2b(v);
        else if constexpr (PHASE==PH_D1)
          p.d1b[(size_t)m*Hh+n] = f2b(v * dsilu_(b2f(p.h1[(size_t)m*Hh+n])));
        else if constexpr (PHASE==PH_UPD1) {
          float g = clip1_(v);
          size_t idx = (size_t)m*Dd+n;
          float m1 = et*p.M1[idx] - lr*g;
          p.M1[idx] = m1;
          p.Wd1[idx] = (1.0f-al)*p.Wd1[idx] + m1;
        }
        else if constexpr (PHASE==PH_UPD2) {
          float g = clip1_(v);
          size_t idx = (size_t)m*Hh+n;
          float m2 = et*p.M2[idx] - lr*g;
          p.M2[idx] = m2;
          p.Wd2[idx] = (1.0f-al)*p.Wd2[idx] + m2;
        }
      }
    }
  }
}

template<int PHASE, int KD>
__global__ __launch_bounds__(256) void gk(Ptrs p){
  gemm_body<PHASE,KD>(p, blockIdx.x, blockIdx.y, nullptr, nullptr);
}
__global__ __launch_bounds__(256) void gk_proj(Ptrs p){
  const float* Wp = blockIdx.z==0 ? p.Wk : (blockIdx.z==1 ? p.Wv : p.Wq);
  ushort_t*    Cp = blockIdx.z==0 ? p.kbuf : (blockIdx.z==1 ? p.vbuf : p.qbuf);
  gemm_body<PH_PROJ,Dd>(p, blockIdx.x, blockIdx.y, Wp, Cp);
}
__global__ __launch_bounds__(256) void gk_d1_upd2(Ptrs p){
  if (blockIdx.z==0) gemm_body<PH_D1,Dd>(p, blockIdx.x, blockIdx.y, nullptr, nullptr);
  else               gemm_body<PH_UPD2,MROW>(p, blockIdx.x, blockIdx.y, nullptr, nullptr);
}

// ---------------- zero the scan state --------------------------------------------
__global__ __launch_bounds__(256)
void zero_k(float* __restrict__ ptr, int n){
  int i = blockIdx.x*256 + threadIdx.x;
  int stride = gridDim.x*256;
  for (; i < n; i += stride) ptr[i] = 0.0f;
}

// ---------------- halo save (last 3 rows of each chunk, pre-conv) ----------------
__global__ void halo_k(const ushort_t* __restrict__ kbuf, const ushort_t* __restrict__ vbuf,
                       const ushort_t* __restrict__ qbuf, ushort_t* __restrict__ halo){
  int bid = blockIdx.x;
  int t = bid / (NCn*Bb);
  int rem = bid % (NCn*Bb);
  int nc = rem / Bb, b = rem % Bb;
  const ushort_t* src = (t==0)?kbuf:((t==1)?vbuf:qbuf);
  ushort_t* dst = halo + (((size_t)t*NCn + nc)*Bb + b)*3*Dd;
  for (int e = threadIdx.x; e < 3*Dd; e += 256){
    int j = e / Dd, d = e % Dd;
    int s = nc*CSc + 61 + j;
    dst[e] = src[((size_t)b*Ss + s)*Dd + d];
  }
}

// ---------------- in-place causal depthwise conv (K=4) ---------------------------
__global__ void conv_k(ushort_t* __restrict__ kbuf, ushort_t* __restrict__ vbuf, ushort_t* __restrict__ qbuf,
                       const float* __restrict__ ckw, const float* __restrict__ ckb,
                       const float* __restrict__ cvw, const float* __restrict__ cvb,
                       const float* __restrict__ cqw, const float* __restrict__ cqb,
                       const ushort_t* __restrict__ halo){
  int bid = blockIdx.x;
  int t = bid / (NCn*Bb);
  int rem = bid % (NCn*Bb);
  int nc = rem / Bb, b = rem % Bb;
  ushort_t* buf = (t==0)?kbuf:((t==1)?vbuf:qbuf);
  const float* cw = (t==0)?ckw:((t==1)?cvw:cqw);
  const float* cb = (t==0)?ckb:((t==1)?cvb:cqb);
  const ushort_t* hl = halo + (((size_t)t*NCn + (nc>0?nc-1:0))*Bb + b)*3*Dd;
  for (int rep=0; rep<2; ++rep){
    int d = threadIdx.x + rep*256;
    float w0 = cw[d*4+0], w1 = cw[d*4+1], w2 = cw[d*4+2], w3 = cw[d*4+3];
    float bias = cb[d];
    float p1, p2, p3;
    if (nc == 0) { p1=p2=p3=0.0f; }
    else { p1 = b2f(hl[2*Dd+d]); p2 = b2f(hl[1*Dd+d]); p3 = b2f(hl[0*Dd+d]); }
    ushort_t* row = buf + ((size_t)b*Ss + nc*CSc)*Dd + d;
    for (int c=0;c<CSc;++c){
      float cur = b2f(row[(size_t)c*Dd]);
      float o = w3*cur + w2*p1 + w1*p2 + w0*p3 + bias;
      p3 = p2; p2 = p1; p1 = cur;
      row[(size_t)c*Dd] = f2b(o);
    }
  }
}

// ---------------- per-chunk scalar gates -----------------------------------------
__global__ __launch_bounds__(256)
void gates_k(const float* __restrict__ x,
             const float* __restrict__ wd, const float* __restrict__ bd,
             const float* __restrict__ wl, const float* __restrict__ bl,
             const float* __restrict__ we, const float* __restrict__ be,
             float* __restrict__ gates){
  int nc = blockIdx.x;
  int wave = threadIdx.x >> 6, lane = threadIdx.x & 63;
  __shared__ float red[4][3];
  float accA=0.f, accL=0.f, accE=0.f;
  float bdv = bd[0], blv = bl[0], bev = be[0];
  for (int pi = wave; pi < Bb*CSc; pi += 4) {
    int b = pi / CSc, c = pi % CSc;
    const float* xr = x + ((size_t)b*Ss + nc*CSc + c)*Dd + lane*8;
    float da=0.f, dl=0.f, de=0.f;
    #pragma unroll
    for (int u=0;u<8;++u){
      float xv = xr[u];
      int d = lane*8+u;
      da += xv*wd[d]; dl += xv*wl[d]; de += xv*we[d];
    }
    #pragma unroll
    for (int off=32; off; off>>=1){
      da += __shfl_down(da, off);
      dl += __shfl_down(dl, off);
      de += __shfl_down(de, off);
    }
    if (lane==0){
      accA += sig_(da + bdv);
      accL += sig_(dl + blv);
      accE += sig_(de + bev);
    }
  }
  if (lane==0){ red[wave][0]=accA; red[wave][1]=accL; red[wave][2]=accE; }
  __syncthreads();
  if (threadIdx.x==0){
    float a=0.f,l=0.f,e=0.f;
    for (int w=0;w<4;w++){ a+=red[w][0]; l+=red[w][1]; e+=red[w][2]; }
    gates[nc]        = a*(1.0f/512.0f);
    gates[NCn+nc]    = l*(1.0f/512.0f);
    gates[2*NCn+nc]  = e*(1.0f/512.0f);
  }
}

extern "C" void kernel_launch(void* const* d_in, const int* in_sizes, int n_in,
                              void* d_out, int out_size, void* d_ws, size_t ws_size,
                              hipStream_t stream) {
  (void)in_sizes; (void)n_in; (void)out_size;
  const float* x       = (const float*)d_in[0];
  const float* Wk      = (const float*)d_in[1];
  const float* Wv      = (const float*)d_in[2];
  const float* Wq      = (const float*)d_in[3];
  const float* Wout    = (const float*)d_in[4];
  const float* ckw     = (const float*)d_in[5];
  const float* ckb     = (const float*)d_in[6];
  const float* cvw     = (const float*)d_in[7];
  const float* cvb     = (const float*)d_in[8];
  const float* cqw     = (const float*)d_in[9];
  const float* cqb     = (const float*)d_in[10];
  const float* w_decay = (const float*)d_in[11];
  const float* b_decay = (const float*)d_in[12];
  const float* w_lr    = (const float*)d_in[13];
  const float* b_lr    = (const float*)d_in[14];
  const float* w_eta   = (const float*)d_in[15];
  const float* b_eta   = (const float*)d_in[16];
  const float* W1      = (const float*)d_in[17];
  const float* W2      = (const float*)d_in[18];

  // ---- workspace carve: fp32 state first, then bf16 buffers ----
  char* base = (char*)d_ws;
  size_t off = 0;
  auto alloc_f = [&](size_t n)->float*   { float* r=(float*)(base+off);   off += n*4; return r; };
  auto alloc_b = [&](size_t n)->ushort_t*{ ushort_t* r=(ushort_t*)(base+off); off += n*2; off=(off+15)&~15ull; return r; };

  float* Wd1  = alloc_f((size_t)Hh*Dd);
  float* M1   = alloc_f((size_t)Hh*Dd);
  float* Wd2  = alloc_f((size_t)Dd*Hh);
  float* M2   = alloc_f((size_t)Dd*Hh);
  float* gates= alloc_f(3*NCn + 4);

  const size_t BSD = (size_t)Bb*Ss*Dd;
  ushort_t* kbuf = alloc_b(BSD);
  ushort_t* vbuf = alloc_b(BSD);
  ushort_t* qbuf = alloc_b(BSD);
  ushort_t* halo = alloc_b((size_t)3*NCn*Bb*3*Dd);
  ushort_t* h1   = alloc_b((size_t)MROW*Hh);
  ushort_t* a1   = alloc_b((size_t)MROW*Hh);
  ushort_t* d1b  = alloc_b((size_t)MROW*Hh);
  ushort_t* d2b  = alloc_b((size_t)MROW*Dd);
  ushort_t* rbuf = alloc_b((size_t)MROW*Dd);

  if (ws_size < off) return;  // clean fail instead of fault

  // zero scan state (Wd1,M1,Wd2,M2 contiguous)
  zero_k<<<512, 256, 0, stream>>>(Wd1, 4*Hh*Dd);

  Ptrs p;
  p.x=x; p.Wk=Wk; p.Wv=Wv; p.Wq=Wq; p.Wout=Wout; p.W1=W1; p.W2=W2;
  p.kbuf=kbuf; p.vbuf=vbuf; p.qbuf=qbuf; p.rbuf=rbuf;
  p.h1=h1; p.a1=a1; p.d1b=d1b; p.d2b=d2b;
  p.Wd1=Wd1; p.M1=M1; p.Wd2=Wd2; p.M2=M2;
  p.gates=gates; p.out=(float*)d_out; p.nc=0;

  // projections: k/v/q = bf16(x) @ bf16(W^T)
  gk_proj<<<dim3(Bb*Ss/64, Dd/64, 3), 256, 0, stream>>>(p);
  halo_k<<<3*NCn*Bb, 256, 0, stream>>>(kbuf, vbuf, qbuf, halo);
  conv_k<<<3*NCn*Bb, 256, 0, stream>>>(kbuf, vbuf, qbuf, ckw, ckb, cvw, cvb, cqw, cqb, halo);
  gates_k<<<NCn, 256, 0, stream>>>(x, w_decay, b_decay, w_lr, b_lr, w_eta, b_eta, gates);

  // sequential chunk scan
  for (int nc = 0; nc < NCn; ++nc) {
    p.nc = nc;
    gk<PH_H1,  Dd>  <<<dim3(MROW/64, Hh/64),   256, 0, stream>>>(p);
    gk<PH_PRED,Hh>  <<<dim3(MROW/64, Dd/64),   256, 0, stream>>>(p);
    gk_d1_upd2      <<<dim3(MROW/64, Hh/64, 2),256, 0, stream>>>(p);
    gk<PH_UPD1,MROW><<<dim3(Hh/64,   Dd/64),   256, 0, stream>>>(p);
    gk<PH_H1Q, Dd>  <<<dim3(MROW/64, Hh/64),   256, 0, stream>>>(p);
    gk<PH_R,   Hh>  <<<dim3(MROW/64, Dd/64),   256, 0, stream>>>(p);
    gk<PH_OUTC,Dd>  <<<dim3(MROW/64, Dd/64),   256, 0, stream>>>(p);
  }
}